// Round 1
// baseline (758.232 us; speedup 1.0000x reference)
//
#include <hip/hip_runtime.h>

// ---------------- problem constants ----------------
#define Bn 4
#define Sn 2048
#define Dn 1024
#define Hn 16
#define DKn 64
#define DFFn 4096
#define Mn (Bn * Sn) // 8192

typedef __bf16 bf16;
typedef __attribute__((ext_vector_type(8))) __bf16 bf16x8;
typedef __attribute__((ext_vector_type(4))) __bf16 bf16x4;
typedef __attribute__((ext_vector_type(8))) unsigned short u16x8;
typedef __attribute__((ext_vector_type(4))) float f32x4;

// ---------------- f32 -> bf16 pack (vectorized, 8 elems/thread) ----------------
__global__ __launch_bounds__(256) void k_cvt_bf16(const float* __restrict__ in,
                                                  bf16* __restrict__ out) {
  size_t i = ((size_t)blockIdx.x * 256 + threadIdx.x) * 8;
  f32x4 a = *(const f32x4*)(in + i);
  f32x4 b = *(const f32x4*)(in + i + 4);
  bf16x8 o;
#pragma unroll
  for (int j = 0; j < 4; ++j) { o[j] = (bf16)a[j]; o[j + 4] = (bf16)b[j]; }
  *(bf16x8*)(out + i) = o;
}

// ---------------- weight transpose + convert: in (K,N) f32 -> out (N,K) bf16 ----------------
__global__ __launch_bounds__(256) void k_transpose_bf16(const float* __restrict__ in,
                                                        bf16* __restrict__ out,
                                                        int K, int N) {
  __shared__ float tile[32][33];
  int n0 = blockIdx.x * 32, k0 = blockIdx.y * 32;
  int tx = threadIdx.x, ty = threadIdx.y;
#pragma unroll
  for (int j = ty; j < 32; j += 8)
    tile[j][tx] = in[(size_t)(k0 + j) * N + n0 + tx];
  __syncthreads();
#pragma unroll
  for (int j = ty; j < 32; j += 8)
    out[(size_t)(n0 + j) * K + k0 + tx] = (bf16)tile[tx][j];
}

// ---------------- bf16 MFMA GEMM: C[M,N] = A[M,K] @ BT[N,K]^T + bias ----------------
// 128x128 block tile, 4 waves (2x2), each wave 64x64 via 4x4 frags of 16x16x32 MFMA.
template <int OUT_BF16, int DO_RELU>
__global__ __launch_bounds__(256) void k_gemm_bt(const bf16* __restrict__ A,
                                                 const bf16* __restrict__ BT,
                                                 const float* __restrict__ bias,
                                                 void* __restrict__ Cptr,
                                                 int Mdim, int Ndim, int Kdim) {
  __shared__ bf16 As[128][40]; // +8 pad: 80B row stride, 16B aligned
  __shared__ bf16 Bs[128][40];
  const int tid = threadIdx.x;
  const int wid = tid >> 6, lane = tid & 63;
  const int l15 = lane & 15, l4 = lane >> 4;
  const int wm = wid >> 1, wn = wid & 1;
  const int m0 = blockIdx.y * 128, n0 = blockIdx.x * 128;

  const f32x4 z4 = {0.f, 0.f, 0.f, 0.f};
  f32x4 acc[4][4];
#pragma unroll
  for (int mi = 0; mi < 4; ++mi)
#pragma unroll
    for (int ni = 0; ni < 4; ++ni) acc[mi][ni] = z4;

  const int arow = tid >> 2;       // 0..63
  const int ac8 = (tid & 3) * 8;   // k-chunk offset
  const size_t aBase = (size_t)(m0 + arow) * Kdim + ac8;
  const size_t bBase = (size_t)(n0 + arow) * Kdim + ac8;

  for (int kt = 0; kt < Kdim; kt += 32) {
    u16x8 av0 = *(const u16x8*)(A + aBase + kt);
    u16x8 av1 = *(const u16x8*)(A + aBase + (size_t)64 * Kdim + kt);
    u16x8 bv0 = *(const u16x8*)(BT + bBase + kt);
    u16x8 bv1 = *(const u16x8*)(BT + bBase + (size_t)64 * Kdim + kt);
    *(u16x8*)&As[arow][ac8] = av0;
    *(u16x8*)&As[arow + 64][ac8] = av1;
    *(u16x8*)&Bs[arow][ac8] = bv0;
    *(u16x8*)&Bs[arow + 64][ac8] = bv1;
    __syncthreads();

    bf16x8 af[4], bfr[4];
#pragma unroll
    for (int mi = 0; mi < 4; ++mi)
      af[mi] = *(const bf16x8*)&As[wm * 64 + mi * 16 + l15][l4 * 8];
#pragma unroll
    for (int ni = 0; ni < 4; ++ni)
      bfr[ni] = *(const bf16x8*)&Bs[wn * 64 + ni * 16 + l15][l4 * 8];
#pragma unroll
    for (int mi = 0; mi < 4; ++mi)
#pragma unroll
      for (int ni = 0; ni < 4; ++ni)
        acc[mi][ni] = __builtin_amdgcn_mfma_f32_16x16x32_bf16(af[mi], bfr[ni],
                                                              acc[mi][ni], 0, 0, 0);
    __syncthreads();
  }

  float* Cf = (float*)Cptr;
  bf16* Cb = (bf16*)Cptr;
  const int row0 = m0 + wm * 64, col0 = n0 + wn * 64;
#pragma unroll
  for (int mi = 0; mi < 4; ++mi)
#pragma unroll
    for (int ni = 0; ni < 4; ++ni) {
      int c = col0 + ni * 16 + l15;
      float bv = bias[c];
      int r0 = row0 + mi * 16 + l4 * 4;
#pragma unroll
      for (int r = 0; r < 4; ++r) {
        float val = acc[mi][ni][r] + bv;
        if (DO_RELU) val = fmaxf(val, 0.f);
        if (OUT_BF16) Cb[(size_t)(r0 + r) * Ndim + c] = (bf16)val;
        else Cf[(size_t)(r0 + r) * Ndim + c] = val;
      }
    }
}

// ---------------- flash attention ----------------
// grid (S/64, B*H), 256 thr (4 waves). Wave w: q rows [qblk*64 + w*16, +16).
__global__ __launch_bounds__(256) void k_attn(const bf16* __restrict__ q,
                                              const bf16* __restrict__ k,
                                              const bf16* __restrict__ v,
                                              const int* __restrict__ mask,
                                              bf16* __restrict__ ctx) {
  __shared__ bf16 Kt[64][72];       // [key][dk]
  __shared__ bf16 Vt[64][72];       // [dk][key] (transposed)
  __shared__ bf16 Ps[4][16][72];    // per-wave P tile [qrow][key]
  const int tid = threadIdx.x, wid = tid >> 6, lane = tid & 63;
  const int l15 = lane & 15, l4 = lane >> 4;
  const int qblk = blockIdx.x, bh = blockIdx.y;
  const int b = bh >> 4, h = bh & 15;
  const int q0 = qblk * 64 + wid * 16;

  // Q fragments (A layout): row l15, k-chunk l4*8 (+32 for second K-step)
  const bf16* qrow = q + (size_t)(b * Sn + q0 + l15) * Dn + h * DKn;
  bf16x8 qf[2];
  qf[0] = *(const bf16x8*)(qrow + l4 * 8);
  qf[1] = *(const bf16x8*)(qrow + 32 + l4 * 8);

  const f32x4 z4 = {0.f, 0.f, 0.f, 0.f};
  f32x4 o[4];
  float mrow[4], lrow[4];
#pragma unroll
  for (int i = 0; i < 4; ++i) { o[i] = z4; mrow[i] = -INFINITY; lrow[i] = 0.f; }

  const int srow = tid >> 3;       // 0..31
  const int sc8 = (tid & 7) * 8;   // 0..56
  const int mbase = b * Sn;

  for (int kb = 0; kb < Sn / 64; ++kb) {
    // stage K (row-major) and V (transposed)
#pragma unroll
    for (int it = 0; it < 2; ++it) {
      int row = srow + it * 32;
      size_t goff = (size_t)(b * Sn + kb * 64 + row) * Dn + h * DKn + sc8;
      *(u16x8*)&Kt[row][sc8] = *(const u16x8*)(k + goff);
      bf16x8 vv = *(const bf16x8*)(v + goff);
#pragma unroll
      for (int i = 0; i < 8; ++i) Vt[sc8 + i][row] = vv[i];
    }
    __syncthreads();

    // scores S = Q . K^T  (16 q x 64 keys per wave)
    f32x4 sc[4];
#pragma unroll
    for (int nf = 0; nf < 4; ++nf) {
      sc[nf] = z4;
#pragma unroll
      for (int ks = 0; ks < 2; ++ks) {
        bf16x8 kf = *(const bf16x8*)&Kt[nf * 16 + l15][ks * 32 + l4 * 8];
        sc[nf] = __builtin_amdgcn_mfma_f32_16x16x32_bf16(qf[ks], kf, sc[nf], 0, 0, 0);
      }
    }
    // scale + mask
#pragma unroll
    for (int nf = 0; nf < 4; ++nf) {
      int key = kb * 64 + nf * 16 + l15;
      int mv = mask[mbase + key];
#pragma unroll
      for (int r = 0; r < 4; ++r) {
        float s = sc[nf][r] * 0.125f;
        if (mv == 0) s = -1e9f;
        sc[nf][r] = s;
      }
    }
    // row max over 64 keys: local over frags, then 16-lane shuffle reduce
    float rmax[4];
#pragma unroll
    for (int r = 0; r < 4; ++r)
      rmax[r] = fmaxf(fmaxf(sc[0][r], sc[1][r]), fmaxf(sc[2][r], sc[3][r]));
#pragma unroll
    for (int off = 8; off; off >>= 1)
#pragma unroll
      for (int r = 0; r < 4; ++r) rmax[r] = fmaxf(rmax[r], __shfl_xor(rmax[r], off));

    float pscale[4];
#pragma unroll
    for (int r = 0; r < 4; ++r) {
      float mnew = fmaxf(mrow[r], rmax[r]);
      pscale[r] = __expf(mrow[r] - mnew); // -inf first iter -> 0
      mrow[r] = mnew;
    }
    // P = exp(S - m), write to per-wave LDS (C layout -> A layout round-trip)
    float psum[4] = {0.f, 0.f, 0.f, 0.f};
#pragma unroll
    for (int nf = 0; nf < 4; ++nf) {
#pragma unroll
      for (int r = 0; r < 4; ++r) {
        float p = __expf(sc[nf][r] - mrow[r]);
        psum[r] += p;
        Ps[wid][l4 * 4 + r][nf * 16 + l15] = (bf16)p;
      }
    }
#pragma unroll
    for (int off = 8; off; off >>= 1)
#pragma unroll
      for (int r = 0; r < 4; ++r) psum[r] += __shfl_xor(psum[r], off);
#pragma unroll
    for (int r = 0; r < 4; ++r) lrow[r] = lrow[r] * pscale[r] + psum[r];
#pragma unroll
    for (int nf = 0; nf < 4; ++nf)
#pragma unroll
      for (int r = 0; r < 4; ++r) o[nf][r] *= pscale[r];

    // O += P . V
#pragma unroll
    for (int ks = 0; ks < 2; ++ks) {
      bf16x8 pa = *(const bf16x8*)&Ps[wid][l15][ks * 32 + l4 * 8];
#pragma unroll
      for (int nf = 0; nf < 4; ++nf) {
        bf16x8 vf = *(const bf16x8*)&Vt[nf * 16 + l15][ks * 32 + l4 * 8];
        o[nf] = __builtin_amdgcn_mfma_f32_16x16x32_bf16(pa, vf, o[nf], 0, 0, 0);
      }
    }
    __syncthreads();
  }

  // epilogue: ctx = O / l
#pragma unroll
  for (int nf = 0; nf < 4; ++nf) {
    int dk = nf * 16 + l15;
#pragma unroll
    for (int r = 0; r < 4; ++r) {
      int s = q0 + l4 * 4 + r;
      ctx[(size_t)(b * Sn + s) * Dn + h * DKn + dk] = (bf16)(o[nf][r] / lrow[r]);
    }
  }
}

// ---------------- residual + LayerNorm (ddof=1, /(std+eps)) ----------------
__global__ __launch_bounds__(256) void k_ln(const float* __restrict__ x,
                                            const float* __restrict__ res,
                                            const float* __restrict__ gamma,
                                            const float* __restrict__ beta,
                                            float* __restrict__ yout,
                                            bf16* __restrict__ ybout) {
  const int row = blockIdx.x, t = threadIdx.x;
  const size_t base = (size_t)row * Dn + t * 4;
  f32x4 a = *(const f32x4*)(x + base);
  f32x4 b = *(const f32x4*)(res + base);
  f32x4 vv;
#pragma unroll
  for (int j = 0; j < 4; ++j) vv[j] = a[j] + b[j];

  float s = vv[0] + vv[1] + vv[2] + vv[3];
#pragma unroll
  for (int off = 32; off; off >>= 1) s += __shfl_xor(s, off);
  __shared__ float red1[4], red2[4];
  if ((t & 63) == 0) red1[t >> 6] = s;
  __syncthreads();
  float mean = (red1[0] + red1[1] + red1[2] + red1[3]) * (1.f / 1024.f);

  float d[4], s2 = 0.f;
#pragma unroll
  for (int j = 0; j < 4; ++j) { d[j] = vv[j] - mean; s2 += d[j] * d[j]; }
#pragma unroll
  for (int off = 32; off; off >>= 1) s2 += __shfl_xor(s2, off);
  if ((t & 63) == 0) red2[t >> 6] = s2;
  __syncthreads();
  float var = (red2[0] + red2[1] + red2[2] + red2[3]) * (1.f / 1023.f);
  float inv = 1.f / (sqrtf(var) + 1e-6f);

  f32x4 g = *(const f32x4*)(gamma + t * 4);
  f32x4 bt = *(const f32x4*)(beta + t * 4);
  f32x4 outv;
  bf16x4 outb;
#pragma unroll
  for (int j = 0; j < 4; ++j) {
    float val = g[j] * d[j] * inv + bt[j];
    outv[j] = val;
    outb[j] = (bf16)val;
  }
  *(f32x4*)(yout + base) = outv;
  if (ybout) *(bf16x4*)(ybout + base) = outb;
}

// ---------------- host launcher ----------------
extern "C" void kernel_launch(void* const* d_in, const int* in_sizes, int n_in,
                              void* d_out, int out_size, void* d_ws, size_t ws_size,
                              hipStream_t stream) {
  const float* x   = (const float*)d_in[0];
  const int*   msk = (const int*)d_in[1];
  const float* Wq  = (const float*)d_in[2];
  const float* bq  = (const float*)d_in[3];
  const float* Wk  = (const float*)d_in[4];
  const float* bk  = (const float*)d_in[5];
  const float* Wv  = (const float*)d_in[6];
  const float* bv  = (const float*)d_in[7];
  const float* Wo  = (const float*)d_in[8];
  const float* bo  = (const float*)d_in[9];
  const float* W1  = (const float*)d_in[10];
  const float* b1  = (const float*)d_in[11];
  const float* W2  = (const float*)d_in[12];
  const float* b2  = (const float*)d_in[13];
  const float* g1  = (const float*)d_in[14];
  const float* be1 = (const float*)d_in[15];
  const float* g2  = (const float*)d_in[16];
  const float* be2 = (const float*)d_in[17];
  float* out = (float*)d_out;

  // workspace layout (all sizes multiples of 256B; overlays noted)
  char* w = (char*)d_ws;
  size_t off = 0;
  auto alloc = [&](size_t bytes) { void* p = w + off; off += (bytes + 255) & ~(size_t)255; return p; };
  bf16* xb  = (bf16*)alloc((size_t)Mn * Dn * 2);       // dead after QKV
  bf16* wqT = (bf16*)alloc((size_t)Dn * Dn * 2);
  bf16* wkT = (bf16*)alloc((size_t)Dn * Dn * 2);
  bf16* wvT = (bf16*)alloc((size_t)Dn * Dn * 2);
  bf16* woT = (bf16*)alloc((size_t)Dn * Dn * 2);
  bf16* w1T = (bf16*)alloc((size_t)Dn * DFFn * 2);
  bf16* w2T = (bf16*)alloc((size_t)DFFn * Dn * 2);
  bf16* qb  = (bf16*)alloc((size_t)Mn * Dn * 2);
  bf16* kb_ = (bf16*)alloc((size_t)Mn * Dn * 2);
  bf16* vb_ = (bf16*)alloc((size_t)Mn * Dn * 2);
  float* attn = (float*)alloc((size_t)Mn * Dn * 4);    // dead after LN1
  float* y    = (float*)alloc((size_t)Mn * Dn * 4);
  bf16* yb    = (bf16*)alloc((size_t)Mn * Dn * 2);
  (void)ws_size; (void)in_sizes; (void)n_in; (void)out_size;
  // overlays (regions dead by the time these are written):
  bf16* ctx = xb;          // written by attn, read by Wo GEMM
  bf16* hh  = qb;          // FF1 out: 64MB spans qb,kb_,vb_ + head of attn (all dead)
  float* ff = (float*)w;   // FF2 out: spans xb..w1T region (all dead by FF2)

  // 1. pack x, transpose weights
  k_cvt_bf16<<<(Mn * Dn) / 2048, 256, 0, stream>>>(x, xb);
  dim3 tb(32, 8);
  k_transpose_bf16<<<dim3(32, 32), tb, 0, stream>>>(Wq, wqT, Dn, Dn);
  k_transpose_bf16<<<dim3(32, 32), tb, 0, stream>>>(Wk, wkT, Dn, Dn);
  k_transpose_bf16<<<dim3(32, 32), tb, 0, stream>>>(Wv, wvT, Dn, Dn);
  k_transpose_bf16<<<dim3(32, 32), tb, 0, stream>>>(Wo, woT, Dn, Dn);
  k_transpose_bf16<<<dim3(128, 32), tb, 0, stream>>>(W1, w1T, Dn, DFFn);
  k_transpose_bf16<<<dim3(32, 128), tb, 0, stream>>>(W2, w2T, DFFn, Dn);

  // 2. QKV projections (bf16 out)
  k_gemm_bt<1, 0><<<dim3(8, 64), 256, 0, stream>>>(xb, wqT, bq, qb, Mn, Dn, Dn);
  k_gemm_bt<1, 0><<<dim3(8, 64), 256, 0, stream>>>(xb, wkT, bk, kb_, Mn, Dn, Dn);
  k_gemm_bt<1, 0><<<dim3(8, 64), 256, 0, stream>>>(xb, wvT, bv, vb_, Mn, Dn, Dn);

  // 3. flash attention
  k_attn<<<dim3(Sn / 64, Bn * Hn), 256, 0, stream>>>(qb, kb_, vb_, msk, ctx);

  // 4. output projection (f32 out)
  k_gemm_bt<0, 0><<<dim3(8, 64), 256, 0, stream>>>(ctx, woT, bo, attn, Mn, Dn, Dn);

  // 5. LN1: y = LN(x + attn)
  k_ln<<<Mn, 256, 0, stream>>>(x, attn, g1, be1, y, yb);

  // 6. FF1: hh = relu(yb @ W1 + b1)  (bf16 out)
  k_gemm_bt<1, 1><<<dim3(32, 64), 256, 0, stream>>>(yb, w1T, b1, hh, Mn, DFFn, Dn);

  // 7. FF2: ff = hh @ W2 + b2  (f32 out)
  k_gemm_bt<0, 0><<<dim3(8, 64), 256, 0, stream>>>(hh, w2T, b2, ff, Mn, Dn, DFFn);

  // 8. LN2: out = LN(y + ff)
  k_ln<<<Mn, 256, 0, stream>>>(y, ff, g2, be2, out, nullptr);
}

// Round 2
// 626.556 us; speedup vs baseline: 1.2102x; 1.2102x over previous
//
#include <hip/hip_runtime.h>

// ---------------- problem constants ----------------
#define Bn 4
#define Sn 2048
#define Dn 1024
#define Hn 16
#define DKn 64
#define DFFn 4096
#define Mn (Bn * Sn) // 8192

typedef __bf16 bf16;
typedef __attribute__((ext_vector_type(8))) __bf16 bf16x8;
typedef __attribute__((ext_vector_type(4))) __bf16 bf16x4;
typedef __attribute__((ext_vector_type(8))) unsigned short u16x8;
typedef __attribute__((ext_vector_type(4))) float f32x4;

// async global->LDS, 16B per lane; LDS dest = wave-uniform base + lane*16
__device__ __forceinline__ void glds16(const bf16* g, bf16* l) {
  __builtin_amdgcn_global_load_lds((const __attribute__((address_space(1))) void*)g,
                                   (__attribute__((address_space(3))) void*)l, 16, 0, 0);
}

// ---------------- f32 -> bf16 pack ----------------
__global__ __launch_bounds__(256) void k_cvt_bf16(const float* __restrict__ in,
                                                  bf16* __restrict__ out) {
  size_t i = ((size_t)blockIdx.x * 256 + threadIdx.x) * 8;
  f32x4 a = *(const f32x4*)(in + i);
  f32x4 b = *(const f32x4*)(in + i + 4);
  bf16x8 o;
#pragma unroll
  for (int j = 0; j < 4; ++j) { o[j] = (bf16)a[j]; o[j + 4] = (bf16)b[j]; }
  *(bf16x8*)(out + i) = o;
}

// ---------------- weight transpose: (K,N) f32 -> (N,K) bf16 ----------------
__global__ __launch_bounds__(256) void k_transpose_bf16(const float* __restrict__ in,
                                                        bf16* __restrict__ out,
                                                        int K, int N) {
  __shared__ float tile[32][33];
  int n0 = blockIdx.x * 32, k0 = blockIdx.y * 32;
  int tx = threadIdx.x, ty = threadIdx.y;
#pragma unroll
  for (int j = ty; j < 32; j += 8)
    tile[j][tx] = in[(size_t)(k0 + j) * N + n0 + tx];
  __syncthreads();
#pragma unroll
  for (int j = ty; j < 32; j += 8)
    out[(size_t)(n0 + j) * K + k0 + tx] = (bf16)tile[tx][j];
}

// ---------------- V transpose: v[b*S+s][h*64+dk] -> vT[(bh*64+dk)][s] ----------------
__global__ __launch_bounds__(256) void k_vt(const bf16* __restrict__ v,
                                            bf16* __restrict__ vT) {
  __shared__ bf16 T[64][72];
  const int t = threadIdx.x;
  const int s0 = blockIdx.x * 64;
  const int bh = blockIdx.y, b = bh >> 4, h = bh & 15;
#pragma unroll
  for (int it = 0; it < 2; ++it) {
    int r = (t >> 3) + it * 32;
    int c = t & 7;
    u16x8 val = *(const u16x8*)(v + (size_t)(b * Sn + s0 + r) * Dn + h * 64 + c * 8);
    *(u16x8*)&T[r][c * 8] = val;
  }
  __syncthreads();
#pragma unroll
  for (int it = 0; it < 2; ++it) {
    int d = (t >> 3) + it * 32;
    int cs = t & 7;
    bf16x8 o;
#pragma unroll
    for (int j = 0; j < 8; ++j) o[j] = T[cs * 8 + j][d];
    *(bf16x8*)(vT + ((size_t)bh * 64 + d) * Sn + s0 + cs * 8) = o;
  }
}

// ---------------- bf16 MFMA GEMM (m97 structure): C = A @ BT^T + bias ----------------
// 128x128 tile, 4 waves (2x2), linear LDS [128][32], global_load_lds width-16.
template <int OUT_BF16, int DO_RELU>
__global__ __launch_bounds__(256) void k_gemm_bt(const bf16* __restrict__ A,
                                                 const bf16* __restrict__ BT,
                                                 const float* __restrict__ bias,
                                                 void* __restrict__ Cptr,
                                                 int Mdim, int Ndim, int Kdim) {
  __shared__ __align__(128) bf16 As[128 * 32];
  __shared__ __align__(128) bf16 Bs[128 * 32];
  const int tid = threadIdx.x;
  const int wid = tid >> 6, lane = tid & 63;
  const int l15 = lane & 15, l4 = lane >> 4;
  const int wm = wid >> 1, wn = wid & 1;
  const int m0 = blockIdx.y * 128, n0 = blockIdx.x * 128;

  const f32x4 z4 = {0.f, 0.f, 0.f, 0.f};
  f32x4 acc[4][4];
#pragma unroll
  for (int mi = 0; mi < 4; ++mi)
#pragma unroll
    for (int ni = 0; ni < 4; ++ni) acc[mi][ni] = z4;

  // staging: each wave covers rows [wid*16,+16) and [64+wid*16,+16) of both tiles
  const int srow = wid * 16 + (lane >> 2);
  const int kc = (lane & 3) * 8;
  const bf16* ga0 = A + (size_t)(m0 + srow) * Kdim + kc;
  const bf16* ga1 = A + (size_t)(m0 + 64 + srow) * Kdim + kc;
  const bf16* gb0 = BT + (size_t)(n0 + srow) * Kdim + kc;
  const bf16* gb1 = BT + (size_t)(n0 + 64 + srow) * Kdim + kc;
  bf16* lA0 = As + wid * 512;
  bf16* lA1 = As + (64 + wid * 16) * 32;
  bf16* lB0 = Bs + wid * 512;
  bf16* lB1 = Bs + (64 + wid * 16) * 32;

  for (int kt = 0; kt < Kdim; kt += 32) {
    glds16(ga0 + kt, lA0);
    glds16(ga1 + kt, lA1);
    glds16(gb0 + kt, lB0);
    glds16(gb1 + kt, lB1);
    __syncthreads();

    bf16x8 af[4], bfr[4];
#pragma unroll
    for (int mi = 0; mi < 4; ++mi)
      af[mi] = *(const bf16x8*)&As[(wm * 64 + mi * 16 + l15) * 32 + l4 * 8];
#pragma unroll
    for (int ni = 0; ni < 4; ++ni)
      bfr[ni] = *(const bf16x8*)&Bs[(wn * 64 + ni * 16 + l15) * 32 + l4 * 8];
#pragma unroll
    for (int mi = 0; mi < 4; ++mi)
#pragma unroll
      for (int ni = 0; ni < 4; ++ni)
        acc[mi][ni] = __builtin_amdgcn_mfma_f32_16x16x32_bf16(af[mi], bfr[ni],
                                                              acc[mi][ni], 0, 0, 0);
    __syncthreads();
  }

  float* Cf = (float*)Cptr;
  bf16* Cb = (bf16*)Cptr;
  const int row0 = m0 + wm * 64, col0 = n0 + wn * 64;
#pragma unroll
  for (int mi = 0; mi < 4; ++mi)
#pragma unroll
    for (int ni = 0; ni < 4; ++ni) {
      int c = col0 + ni * 16 + l15;
      float bv = bias[c];
      int r0 = row0 + mi * 16 + l4 * 4;
#pragma unroll
      for (int r = 0; r < 4; ++r) {
        float val = acc[mi][ni][r] + bv;
        if (DO_RELU) val = fmaxf(val, 0.f);
        if (OUT_BF16) Cb[(size_t)(r0 + r) * Ndim + c] = (bf16)val;
        else Cf[(size_t)(r0 + r) * Ndim + c] = val;
      }
    }
}

// ---------------- flash attention ----------------
// grid (S/128, B*H), 256 thr (4 waves), wave owns 32 q rows.
// K, V^T tiles glds-staged with pre-swizzled source (chunk ^= row&7); P per-wave LDS.
__global__ __launch_bounds__(256) void k_attn(const bf16* __restrict__ q,
                                              const bf16* __restrict__ k,
                                              const bf16* __restrict__ vT,
                                              const int* __restrict__ mask,
                                              bf16* __restrict__ ctx) {
  __shared__ __align__(128) bf16 Kt[64 * 64];     // swizzled [key][d]
  __shared__ __align__(128) bf16 Vt[64 * 64];     // swizzled [dk][key]
  __shared__ __align__(128) bf16 Ps[4][32 * 64];  // per-wave swizzled [qlocal][key]
  const int tid = threadIdx.x, wid = tid >> 6, lane = tid & 63;
  const int l15 = lane & 15, l4 = lane >> 4;
  const int bh = blockIdx.y, b = bh >> 4, h = bh & 15;
  const int q0 = blockIdx.x * 128 + wid * 32;

  // Q fragments: [mi][ks], row = q0 + mi*16 + l15, k-chunk ks*32 + l4*8
  bf16x8 qf[2][2];
#pragma unroll
  for (int mi = 0; mi < 2; ++mi)
#pragma unroll
    for (int ks = 0; ks < 2; ++ks)
      qf[mi][ks] = *(const bf16x8*)(q + (size_t)(b * Sn + q0 + mi * 16 + l15) * Dn +
                                    h * 64 + ks * 32 + l4 * 8);

  const f32x4 z4 = {0.f, 0.f, 0.f, 0.f};
  f32x4 o[2][4];
  float mr[2][4], lr[2][4];
#pragma unroll
  for (int mi = 0; mi < 2; ++mi)
#pragma unroll
    for (int r = 0; r < 4; ++r) {
      mr[mi][r] = -INFINITY; lr[mi][r] = 0.f;
#pragma unroll
      for (int nf = 0; nf < 4; ++nf) o[mi][nf] = z4;
    }

  // staging lane geometry: 8 rows x 8 chunks per wave-instr; source chunk pre-swizzled
  const int lrow = lane >> 3;                  // row within 8-row segment
  const int lchg = (lane & 7) ^ (lrow & 7);    // swizzled source chunk
  bf16* ps_w = &Ps[wid][0];

  for (int kb = 0; kb < Sn / 64; ++kb) {
    __syncthreads();  // prev tile fully consumed
#pragma unroll
    for (int s = 0; s < 2; ++s) {
      int row = (wid + 4 * s) * 8 + lrow;
      glds16(k + (size_t)(b * Sn + kb * 64 + row) * Dn + h * 64 + lchg * 8,
             Kt + (wid + 4 * s) * 512);
      glds16(vT + ((size_t)bh * 64 + row) * Sn + kb * 64 + lchg * 8,
             Vt + (wid + 4 * s) * 512);
    }
    __syncthreads();  // vmcnt drained -> tiles ready

    // S = Q K^T : per wave 32q x 64keys
    f32x4 sc[2][4];
#pragma unroll
    for (int mi = 0; mi < 2; ++mi)
#pragma unroll
      for (int nf = 0; nf < 4; ++nf) sc[mi][nf] = z4;
#pragma unroll
    for (int ks = 0; ks < 2; ++ks) {
      bf16x8 kf[4];
#pragma unroll
      for (int nf = 0; nf < 4; ++nf) {
        int row = nf * 16 + l15;
        int ch = (ks * 4 + l4) ^ (row & 7);
        kf[nf] = *(const bf16x8*)&Kt[row * 64 + ch * 8];
      }
#pragma unroll
      for (int mi = 0; mi < 2; ++mi)
#pragma unroll
        for (int nf = 0; nf < 4; ++nf)
          sc[mi][nf] = __builtin_amdgcn_mfma_f32_16x16x32_bf16(qf[mi][ks], kf[nf],
                                                               sc[mi][nf], 0, 0, 0);
    }

    // scale + mask (replace semantics, faithful to ref)
    int mv[4];
#pragma unroll
    for (int nf = 0; nf < 4; ++nf) mv[nf] = mask[b * Sn + kb * 64 + nf * 16 + l15];
#pragma unroll
    for (int mi = 0; mi < 2; ++mi)
#pragma unroll
      for (int nf = 0; nf < 4; ++nf)
#pragma unroll
        for (int r = 0; r < 4; ++r) {
          float s = sc[mi][nf][r] * 0.125f;
          sc[mi][nf][r] = mv[nf] ? s : -1e9f;
        }

    // row max over 64 keys (in-lane over nf, then 16-lane shuffle)
    float rmax[2][4];
#pragma unroll
    for (int mi = 0; mi < 2; ++mi)
#pragma unroll
      for (int r = 0; r < 4; ++r)
        rmax[mi][r] = fmaxf(fmaxf(sc[mi][0][r], sc[mi][1][r]),
                            fmaxf(sc[mi][2][r], sc[mi][3][r]));
#pragma unroll
    for (int off = 8; off; off >>= 1)
#pragma unroll
      for (int mi = 0; mi < 2; ++mi)
#pragma unroll
        for (int r = 0; r < 4; ++r)
          rmax[mi][r] = fmaxf(rmax[mi][r], __shfl_xor(rmax[mi][r], off));

    float psc[2][4];
#pragma unroll
    for (int mi = 0; mi < 2; ++mi)
#pragma unroll
      for (int r = 0; r < 4; ++r) {
        float mn = fmaxf(mr[mi][r], rmax[mi][r]);
        psc[mi][r] = __expf(mr[mi][r] - mn);
        mr[mi][r] = mn;
      }

    // P = exp(S-m): accumulate row-sum, write to per-wave swizzled LDS
    float psum[2][4] = {{0.f, 0.f, 0.f, 0.f}, {0.f, 0.f, 0.f, 0.f}};
#pragma unroll
    for (int mi = 0; mi < 2; ++mi)
#pragma unroll
      for (int nf = 0; nf < 4; ++nf)
#pragma unroll
        for (int r = 0; r < 4; ++r) {
          float p = __expf(sc[mi][nf][r] - mr[mi][r]);
          psum[mi][r] += p;
          int ql = mi * 16 + l4 * 4 + r;
          int key = nf * 16 + l15;
          int ch = (key >> 3) ^ (ql & 7);
          ps_w[ql * 64 + ch * 8 + (key & 7)] = (bf16)p;
        }
#pragma unroll
    for (int off = 8; off; off >>= 1)
#pragma unroll
      for (int mi = 0; mi < 2; ++mi)
#pragma unroll
        for (int r = 0; r < 4; ++r) psum[mi][r] += __shfl_xor(psum[mi][r], off);
#pragma unroll
    for (int mi = 0; mi < 2; ++mi)
#pragma unroll
      for (int r = 0; r < 4; ++r) lr[mi][r] = lr[mi][r] * psc[mi][r] + psum[mi][r];
#pragma unroll
    for (int mi = 0; mi < 2; ++mi)
#pragma unroll
      for (int nf = 0; nf < 4; ++nf)
#pragma unroll
        for (int r = 0; r < 4; ++r) o[mi][nf][r] *= psc[mi][r];

    // O += P V  (Ps is per-wave: lgkmcnt dep only, no barrier)
#pragma unroll
    for (int ks = 0; ks < 2; ++ks) {
      bf16x8 pa[2], vf[4];
#pragma unroll
      for (int mi = 0; mi < 2; ++mi) {
        int row = mi * 16 + l15;
        int ch = (ks * 4 + l4) ^ (row & 7);
        pa[mi] = *(const bf16x8*)&ps_w[row * 64 + ch * 8];
      }
#pragma unroll
      for (int nf = 0; nf < 4; ++nf) {
        int row = nf * 16 + l15;
        int ch = (ks * 4 + l4) ^ (row & 7);
        vf[nf] = *(const bf16x8*)&Vt[row * 64 + ch * 8];
      }
#pragma unroll
      for (int mi = 0; mi < 2; ++mi)
#pragma unroll
        for (int nf = 0; nf < 4; ++nf)
          o[mi][nf] = __builtin_amdgcn_mfma_f32_16x16x32_bf16(pa[mi], vf[nf],
                                                              o[mi][nf], 0, 0, 0);
    }
  }

  // epilogue: ctx = O / l
#pragma unroll
  for (int mi = 0; mi < 2; ++mi)
#pragma unroll
    for (int r = 0; r < 4; ++r) {
      float inv = 1.f / lr[mi][r];
      int qrow = q0 + mi * 16 + l4 * 4 + r;
#pragma unroll
      for (int nf = 0; nf < 4; ++nf) {
        int dk = nf * 16 + l15;
        ctx[(size_t)(b * Sn + qrow) * Dn + h * 64 + dk] = (bf16)(o[mi][nf][r] * inv);
      }
    }
}

// ---------------- residual + LayerNorm (ddof=1, /(std+eps)) ----------------
__global__ __launch_bounds__(256) void k_ln(const float* __restrict__ x,
                                            const float* __restrict__ res,
                                            const float* __restrict__ gamma,
                                            const float* __restrict__ beta,
                                            float* __restrict__ yout,
                                            bf16* __restrict__ ybout) {
  const int row = blockIdx.x, t = threadIdx.x;
  const size_t base = (size_t)row * Dn + t * 4;
  f32x4 a = *(const f32x4*)(x + base);
  f32x4 b = *(const f32x4*)(res + base);
  f32x4 vv;
#pragma unroll
  for (int j = 0; j < 4; ++j) vv[j] = a[j] + b[j];

  float s = vv[0] + vv[1] + vv[2] + vv[3];
#pragma unroll
  for (int off = 32; off; off >>= 1) s += __shfl_xor(s, off);
  __shared__ float red1[4], red2[4];
  if ((t & 63) == 0) red1[t >> 6] = s;
  __syncthreads();
  float mean = (red1[0] + red1[1] + red1[2] + red1[3]) * (1.f / 1024.f);

  float d[4], s2 = 0.f;
#pragma unroll
  for (int j = 0; j < 4; ++j) { d[j] = vv[j] - mean; s2 += d[j] * d[j]; }
#pragma unroll
  for (int off = 32; off; off >>= 1) s2 += __shfl_xor(s2, off);
  if ((t & 63) == 0) red2[t >> 6] = s2;
  __syncthreads();
  float var = (red2[0] + red2[1] + red2[2] + red2[3]) * (1.f / 1023.f);
  float inv = 1.f / (sqrtf(var) + 1e-6f);

  f32x4 g = *(const f32x4*)(gamma + t * 4);
  f32x4 bt = *(const f32x4*)(beta + t * 4);
  f32x4 outv;
  bf16x4 outb;
#pragma unroll
  for (int j = 0; j < 4; ++j) {
    float val = g[j] * d[j] * inv + bt[j];
    outv[j] = val;
    outb[j] = (bf16)val;
  }
  *(f32x4*)(yout + base) = outv;
  if (ybout) *(bf16x4*)(ybout + base) = outb;
}

// ---------------- host launcher ----------------
extern "C" void kernel_launch(void* const* d_in, const int* in_sizes, int n_in,
                              void* d_out, int out_size, void* d_ws, size_t ws_size,
                              hipStream_t stream) {
  const float* x   = (const float*)d_in[0];
  const int*   msk = (const int*)d_in[1];
  const float* Wq  = (const float*)d_in[2];
  const float* bq  = (const float*)d_in[3];
  const float* Wk  = (const float*)d_in[4];
  const float* bk  = (const float*)d_in[5];
  const float* Wv  = (const float*)d_in[6];
  const float* bv  = (const float*)d_in[7];
  const float* Wo  = (const float*)d_in[8];
  const float* bo  = (const float*)d_in[9];
  const float* W1  = (const float*)d_in[10];
  const float* b1  = (const float*)d_in[11];
  const float* W2  = (const float*)d_in[12];
  const float* b2  = (const float*)d_in[13];
  const float* g1  = (const float*)d_in[14];
  const float* be1 = (const float*)d_in[15];
  const float* g2  = (const float*)d_in[16];
  const float* be2 = (const float*)d_in[17];
  float* out = (float*)d_out;

  char* w = (char*)d_ws;
  size_t off = 0;
  auto alloc = [&](size_t bytes) { void* p = w + off; off += (bytes + 255) & ~(size_t)255; return p; };
  bf16* xb  = (bf16*)alloc((size_t)Mn * Dn * 2);       // dead after QKV -> vT overlay
  bf16* wqT = (bf16*)alloc((size_t)Dn * Dn * 2);
  bf16* wkT = (bf16*)alloc((size_t)Dn * Dn * 2);
  bf16* wvT = (bf16*)alloc((size_t)Dn * Dn * 2);
  bf16* woT = (bf16*)alloc((size_t)Dn * Dn * 2);
  bf16* w1T = (bf16*)alloc((size_t)Dn * DFFn * 2);
  bf16* w2T = (bf16*)alloc((size_t)DFFn * Dn * 2);
  bf16* qb  = (bf16*)alloc((size_t)Mn * Dn * 2);
  bf16* kb_ = (bf16*)alloc((size_t)Mn * Dn * 2);
  bf16* vb_ = (bf16*)alloc((size_t)Mn * Dn * 2);
  float* attn = (float*)alloc((size_t)Mn * Dn * 4);    // dead after LN1
  float* y    = (float*)alloc((size_t)Mn * Dn * 4);
  bf16* yb    = (bf16*)alloc((size_t)Mn * Dn * 2);
  (void)ws_size; (void)in_sizes; (void)n_in; (void)out_size;
  // overlays (dead-by-then regions):
  bf16* vT  = xb;          // built after QKV GEMMs (xb dead), read by attn
  bf16* ctx = vb_;         // vb_ dead after k_vt; written by attn, read by Wo
  bf16* hh  = qb;          // FF1 out 64MB: spans qb,kb_,vb_(ctx dead),attn head
  float* ff = (float*)w;   // FF2 out 32MB: spans xb/vT + wqT..w1T (all dead)

  // 1. pack x, transpose weights
  k_cvt_bf16<<<(Mn * Dn) / 2048, 256, 0, stream>>>(x, xb);
  dim3 tb(32, 8);
  k_transpose_bf16<<<dim3(32, 32), tb, 0, stream>>>(Wq, wqT, Dn, Dn);
  k_transpose_bf16<<<dim3(32, 32), tb, 0, stream>>>(Wk, wkT, Dn, Dn);
  k_transpose_bf16<<<dim3(32, 32), tb, 0, stream>>>(Wv, wvT, Dn, Dn);
  k_transpose_bf16<<<dim3(32, 32), tb, 0, stream>>>(Wo, woT, Dn, Dn);
  k_transpose_bf16<<<dim3(128, 32), tb, 0, stream>>>(W1, w1T, Dn, DFFn);
  k_transpose_bf16<<<dim3(32, 128), tb, 0, stream>>>(W2, w2T, DFFn, Dn);

  // 2. QKV projections
  k_gemm_bt<1, 0><<<dim3(8, 64), 256, 0, stream>>>(xb, wqT, bq, qb, Mn, Dn, Dn);
  k_gemm_bt<1, 0><<<dim3(8, 64), 256, 0, stream>>>(xb, wkT, bk, kb_, Mn, Dn, Dn);
  k_gemm_bt<1, 0><<<dim3(8, 64), 256, 0, stream>>>(xb, wvT, bv, vb_, Mn, Dn, Dn);

  // 3. V transpose + flash attention
  k_vt<<<dim3(Sn / 64, Bn * Hn), 256, 0, stream>>>(vb_, vT);
  k_attn<<<dim3(Sn / 128, Bn * Hn), 256, 0, stream>>>(qb, kb_, vT, msk, ctx);

  // 4. output projection
  k_gemm_bt<0, 0><<<dim3(8, 64), 256, 0, stream>>>(ctx, woT, bo, attn, Mn, Dn, Dn);

  // 5. LN1
  k_ln<<<Mn, 256, 0, stream>>>(x, attn, g1, be1, y, yb);

  // 6. FF1
  k_gemm_bt<1, 1><<<dim3(32, 64), 256, 0, stream>>>(yb, w1T, b1, hh, Mn, DFFn, Dn);

  // 7. FF2
  k_gemm_bt<0, 0><<<dim3(8, 64), 256, 0, stream>>>(hh, w2T, b2, ff, Mn, Dn, DFFn);

  // 8. LN2
  k_ln<<<Mn, 256, 0, stream>>>(y, ff, g2, be2, out, nullptr);
}

// Round 4
// 531.383 us; speedup vs baseline: 1.4269x; 1.1791x over previous
//
#include <hip/hip_runtime.h>

// ---------------- problem constants ----------------
#define Bn 4
#define Sn 2048
#define Dn 1024
#define Hn 16
#define DKn 64
#define DFFn 4096
#define Mn (Bn * Sn) // 8192

typedef __bf16 bf16;
typedef __attribute__((ext_vector_type(8))) __bf16 bf16x8;
typedef __attribute__((ext_vector_type(4))) __bf16 bf16x4;
typedef __attribute__((ext_vector_type(8))) unsigned short u16x8;
typedef __attribute__((ext_vector_type(4))) float f32x4;
typedef __attribute__((ext_vector_type(16))) float f32x16;

#define LOG2E_DIV8 0.18033688011112042f  // 0.125 * log2(e)

// raw v_exp_f32 (2^x); avoids glibc __exp2f macro collision
__device__ __forceinline__ float exp2fast(float x) {
  return __builtin_amdgcn_exp2f(x);
}

// async global->LDS, 16B per lane; LDS dest = wave-uniform base + lane*16
__device__ __forceinline__ void glds16(const bf16* g, bf16* l) {
  __builtin_amdgcn_global_load_lds((const __attribute__((address_space(1))) void*)g,
                                   (__attribute__((address_space(3))) void*)l, 16, 0, 0);
}

__device__ __forceinline__ unsigned int pkbf16(float a, float b) {
  union { __bf16 h[2]; unsigned int u; } x;
  x.h[0] = (__bf16)a; x.h[1] = (__bf16)b;
  return x.u;
}

// ---------------- f32 -> bf16 pack ----------------
__global__ __launch_bounds__(256) void k_cvt_bf16(const float* __restrict__ in,
                                                  bf16* __restrict__ out) {
  size_t i = ((size_t)blockIdx.x * 256 + threadIdx.x) * 8;
  f32x4 a = *(const f32x4*)(in + i);
  f32x4 b = *(const f32x4*)(in + i + 4);
  bf16x8 o;
#pragma unroll
  for (int j = 0; j < 4; ++j) { o[j] = (bf16)a[j]; o[j + 4] = (bf16)b[j]; }
  *(bf16x8*)(out + i) = o;
}

// ---------------- weight transpose: (K,N) f32 -> (N,K) bf16 ----------------
__global__ __launch_bounds__(256) void k_transpose_bf16(const float* __restrict__ in,
                                                        bf16* __restrict__ out,
                                                        int K, int N) {
  __shared__ float tile[32][33];
  int n0 = blockIdx.x * 32, k0 = blockIdx.y * 32;
  int tx = threadIdx.x, ty = threadIdx.y;
#pragma unroll
  for (int j = ty; j < 32; j += 8)
    tile[j][tx] = in[(size_t)(k0 + j) * N + n0 + tx];
  __syncthreads();
#pragma unroll
  for (int j = ty; j < 32; j += 8)
    out[(size_t)(n0 + j) * K + k0 + tx] = (bf16)tile[tx][j];
}

// ---------------- V transpose: v[b*S+s][h*64+dk] -> vT[(bh*64+dk)][s] ----------------
__global__ __launch_bounds__(256) void k_vt(const bf16* __restrict__ v,
                                            bf16* __restrict__ vT) {
  __shared__ bf16 T[64][72];
  const int t = threadIdx.x;
  const int s0 = blockIdx.x * 64;
  const int bh = blockIdx.y, b = bh >> 4, h = bh & 15;
#pragma unroll
  for (int it = 0; it < 2; ++it) {
    int r = (t >> 3) + it * 32;
    int c = t & 7;
    u16x8 val = *(const u16x8*)(v + (size_t)(b * Sn + s0 + r) * Dn + h * 64 + c * 8);
    *(u16x8*)&T[r][c * 8] = val;
  }
  __syncthreads();
#pragma unroll
  for (int it = 0; it < 2; ++it) {
    int d = (t >> 3) + it * 32;
    int cs = t & 7;
    bf16x8 o;
#pragma unroll
    for (int j = 0; j < 8; ++j) o[j] = T[cs * 8 + j][d];
    *(bf16x8*)(vT + ((size_t)bh * 64 + d) * Sn + s0 + cs * 8) = o;
  }
}

// ---------------- bf16 MFMA GEMM (m97 structure + XCD swizzle) ----------------
template <int OUT_BF16, int DO_RELU>
__global__ __launch_bounds__(256) void k_gemm_bt(const bf16* __restrict__ A,
                                                 const bf16* __restrict__ BT,
                                                 const float* __restrict__ bias,
                                                 void* __restrict__ Cptr,
                                                 int Mdim, int Ndim, int Kdim,
                                                 float oscale) {
  __shared__ __align__(128) bf16 As[128 * 32];
  __shared__ __align__(128) bf16 Bs[128 * 32];
  const int tid = threadIdx.x;
  const int wid = tid >> 6, lane = tid & 63;
  const int l15 = lane & 15, l4 = lane >> 4;
  const int wm = wid >> 1, wn = wid & 1;

  // XCD-chunked block swizzle (bijective when nwg % 8 == 0)
  const int gx = gridDim.x;
  int lin = blockIdx.y * gx + blockIdx.x;
  const int nwg = gx * gridDim.y;
  if ((nwg & 7) == 0) lin = (lin & 7) * (nwg >> 3) + (lin >> 3);
  const int m0 = (lin / gx) * 128, n0 = (lin % gx) * 128;

  const f32x4 z4 = {0.f, 0.f, 0.f, 0.f};
  f32x4 acc[4][4];
#pragma unroll
  for (int mi = 0; mi < 4; ++mi)
#pragma unroll
    for (int ni = 0; ni < 4; ++ni) acc[mi][ni] = z4;

  const int srow = wid * 16 + (lane >> 2);
  const int kc = (lane & 3) * 8;
  const bf16* ga0 = A + (size_t)(m0 + srow) * Kdim + kc;
  const bf16* ga1 = A + (size_t)(m0 + 64 + srow) * Kdim + kc;
  const bf16* gb0 = BT + (size_t)(n0 + srow) * Kdim + kc;
  const bf16* gb1 = BT + (size_t)(n0 + 64 + srow) * Kdim + kc;
  bf16* lA0 = As + wid * 512;
  bf16* lA1 = As + (64 + wid * 16) * 32;
  bf16* lB0 = Bs + wid * 512;
  bf16* lB1 = Bs + (64 + wid * 16) * 32;

  for (int kt = 0; kt < Kdim; kt += 32) {
    glds16(ga0 + kt, lA0);
    glds16(ga1 + kt, lA1);
    glds16(gb0 + kt, lB0);
    glds16(gb1 + kt, lB1);
    __syncthreads();

    bf16x8 af[4], bfr[4];
#pragma unroll
    for (int mi = 0; mi < 4; ++mi)
      af[mi] = *(const bf16x8*)&As[(wm * 64 + mi * 16 + l15) * 32 + l4 * 8];
#pragma unroll
    for (int ni = 0; ni < 4; ++ni)
      bfr[ni] = *(const bf16x8*)&Bs[(wn * 64 + ni * 16 + l15) * 32 + l4 * 8];
#pragma unroll
    for (int mi = 0; mi < 4; ++mi)
#pragma unroll
      for (int ni = 0; ni < 4; ++ni)
        acc[mi][ni] = __builtin_amdgcn_mfma_f32_16x16x32_bf16(af[mi], bfr[ni],
                                                              acc[mi][ni], 0, 0, 0);
    __syncthreads();
  }

  float* Cf = (float*)Cptr;
  bf16* Cb = (bf16*)Cptr;
  const int row0 = m0 + wm * 64, col0 = n0 + wn * 64;
#pragma unroll
  for (int mi = 0; mi < 4; ++mi)
#pragma unroll
    for (int ni = 0; ni < 4; ++ni) {
      int c = col0 + ni * 16 + l15;
      float bv = bias[c];
      int r0 = row0 + mi * 16 + l4 * 4;
#pragma unroll
      for (int r = 0; r < 4; ++r) {
        float val = (acc[mi][ni][r] + bv) * oscale;
        if (DO_RELU) val = fmaxf(val, 0.f);
        if (OUT_BF16) Cb[(size_t)(r0 + r) * Ndim + c] = (bf16)val;
        else Cf[(size_t)(r0 + r) * Ndim + c] = val;
      }
    }
}

// ---------------- flash attention, swapped-operand 32x32 MFMA ----------------
// grid (S/128, B*H) XCD-swizzled, 256 thr (4 waves), wave owns 32 q rows.
// S^T = mfma(K, Q): lane holds P[q=lane&31][16 keys] per kf frag (crow layout).
// O^T = mfma(V^T, P^T): lane holds O[q=lane&31][dk crow] -> scalar m/l/psc per lane.
// Q pre-scaled by 0.125*log2e in the Q-GEMM epilogue; softmax in exp2 domain.
__global__ __launch_bounds__(256) void k_attn(const bf16* __restrict__ q,
                                              const bf16* __restrict__ k,
                                              const bf16* __restrict__ vT,
                                              const int* __restrict__ mask,
                                              bf16* __restrict__ ctx) {
  __shared__ __align__(128) bf16 Kt[2][64 * 64];  // [key][dk], f-swizzled
  __shared__ __align__(128) bf16 Vt[2][64 * 64];  // [dk][key], f-swizzled
  __shared__ float Mb[Sn];                        // additive mask bias (log2 units)
  const int tid = threadIdx.x, wid = tid >> 6, lane = tid & 63;
  const int q31 = lane & 31, hi = lane >> 5;

  // XCD-chunked swizzle: each XCD gets contiguous run of (bh, qblk) blocks
  int lin = blockIdx.y * gridDim.x + blockIdx.x;  // gridDim = (16, 64) -> 1024
  lin = (lin & 7) * 128 + (lin >> 3);
  const int qblk = lin & 15, bh = lin >> 4;
  const int b = bh >> 4, h = bh & 15;
  const int q0 = qblk * 128 + wid * 32;

  // mask bias -> LDS (once per block)
  for (int i = tid; i < Sn; i += 256)
    Mb[i] = mask[b * Sn + i] ? 0.f : -1.44269504e9f;

  // Q B-fragments: qf[t] = Q[q0+q31][t*16 + hi*8 .. +8], t = dk-step
  bf16x8 qf[4];
#pragma unroll
  for (int t = 0; t < 4; ++t)
    qf[t] = *(const bf16x8*)(q + (size_t)(b * Sn + q0 + q31) * Dn + h * 64 +
                             t * 16 + hi * 8);

  f32x16 o[2];
  o[0] = {}; o[1] = {};
  float mr = -INFINITY, lr = 0.f;

  // staging: per glds instr 8 rows x 8 chunks; source chunk pre-swizzled with
  // f(row) = (row&7) ^ ((row>>3)&3) so 32-row x 2-chunk reads are 2-way (free)
  const int lrow = lane >> 3;
  const int lch0 = lane & 7;

  for (int kb = 0; kb < Sn / 64; ++kb) {
    const int cur = kb & 1;
    if (kb == 0) {
#pragma unroll
      for (int s = 0; s < 2; ++s) {
        int row = (wid + 4 * s) * 8 + lrow;
        int ch = lch0 ^ (lrow ^ ((wid + 4 * s) & 3));
        glds16(k + (size_t)(b * Sn + row) * Dn + h * 64 + ch * 8,
               &Kt[0][(wid + 4 * s) * 512]);
        glds16(vT + ((size_t)bh * 64 + row) * Sn + ch * 8,
               &Vt[0][(wid + 4 * s) * 512]);
      }
      __syncthreads();
    }
    if (kb + 1 < Sn / 64) {  // prefetch next tile into other buffer
#pragma unroll
      for (int s = 0; s < 2; ++s) {
        int row = (wid + 4 * s) * 8 + lrow;
        int ch = lch0 ^ (lrow ^ ((wid + 4 * s) & 3));
        glds16(k + (size_t)(b * Sn + (kb + 1) * 64 + row) * Dn + h * 64 + ch * 8,
               &Kt[cur ^ 1][(wid + 4 * s) * 512]);
        glds16(vT + ((size_t)bh * 64 + row) * Sn + (kb + 1) * 64 + ch * 8,
               &Vt[cur ^ 1][(wid + 4 * s) * 512]);
      }
    }

    // S^T = K . Q^T : sc[kf] covers keys kf*32+crow(r,hi), q = q31
    f32x16 sc[2];
    sc[0] = {}; sc[1] = {};
#pragma unroll
    for (int t = 0; t < 4; ++t) {
#pragma unroll
      for (int kf = 0; kf < 2; ++kf) {
        int row = kf * 32 + q31;
        int ch = (t * 2 + hi) ^ ((row & 7) ^ ((row >> 3) & 3));
        bf16x8 kfr = *(const bf16x8*)&Kt[cur][row * 64 + ch * 8];
        sc[kf] = __builtin_amdgcn_mfma_f32_32x32x16_bf16(kfr, qf[t], sc[kf], 0, 0, 0);
      }
    }

    // + mask bias (keys grouped 4-consecutive per reg quad)
#pragma unroll
    for (int kf = 0; kf < 2; ++kf)
#pragma unroll
      for (int rg = 0; rg < 4; ++rg) {
        f32x4 mb4 = *(const f32x4*)&Mb[kb * 64 + kf * 32 + rg * 8 + 4 * hi];
#pragma unroll
        for (int j = 0; j < 4; ++j) sc[kf][rg * 4 + j] += mb4[j];
      }

    // row max: 31 in-lane fmax + half exchange
    float rmax = sc[0][0];
#pragma unroll
    for (int kf = 0; kf < 2; ++kf)
#pragma unroll
      for (int i = 0; i < 16; ++i)
        if (kf | i) rmax = fmaxf(rmax, sc[kf][i]);
    rmax = fmaxf(rmax, __shfl_xor(rmax, 32));

    // defer-max: rescale only when max grew beyond 2^8
    if (!__all(rmax <= mr + 8.f)) {
      float mnew = fmaxf(mr, rmax);
      float psc = exp2fast(mr - mnew);
      mr = mnew;
      lr *= psc;
#pragma unroll
      for (int af = 0; af < 2; ++af)
#pragma unroll
        for (int i = 0; i < 16; ++i) o[af][i] *= psc;
    }

    // P = exp2(S - m) in place; row-sum
    float psum = 0.f;
#pragma unroll
    for (int kf = 0; kf < 2; ++kf)
#pragma unroll
      for (int i = 0; i < 16; ++i) {
        float p = exp2fast(sc[kf][i] - mr);
        sc[kf][i] = p;
        psum += p;
      }
    psum += __shfl_xor(psum, 32);
    lr += psum;

    // O^T += V^T . P^T : build P B-frags in-register (pack + half exchange)
#pragma unroll
    for (int ks = 0; ks < 4; ++ks) {
      const int kf = ks >> 1, R = (ks & 1) * 8;
      unsigned int a0 = pkbf16(sc[kf][R + 0], sc[kf][R + 1]);
      unsigned int a1 = pkbf16(sc[kf][R + 2], sc[kf][R + 3]);
      unsigned int b0 = pkbf16(sc[kf][R + 4], sc[kf][R + 5]);
      unsigned int b1 = pkbf16(sc[kf][R + 6], sc[kf][R + 7]);
      unsigned int sxa0 = __shfl_xor(a0, 32), sxa1 = __shfl_xor(a1, 32);
      unsigned int sxb0 = __shfl_xor(b0, 32), sxb1 = __shfl_xor(b1, 32);
      union { unsigned int w[4]; bf16x8 v; } pf;
      pf.w[0] = hi ? sxb0 : a0;
      pf.w[1] = hi ? sxb1 : a1;
      pf.w[2] = hi ? b0 : sxa0;
      pf.w[3] = hi ? b1 : sxa1;
#pragma unroll
      for (int af = 0; af < 2; ++af) {
        int row = af * 32 + q31;
        int ch = (ks * 2 + hi) ^ ((row & 7) ^ ((row >> 3) & 3));
        bf16x8 vfr = *(const bf16x8*)&Vt[cur][row * 64 + ch * 8];
        o[af] = __builtin_amdgcn_mfma_f32_32x32x16_bf16(vfr, pf.v, o[af], 0, 0, 0);
      }
    }
    __syncthreads();  // drains prefetch vmcnt + protects buffer swap
  }

  // epilogue: ctx[q][dk] = O^T / l  (lane owns q = q0+q31; dk = af*32+rg*8+4hi+j)
  float inv = 1.f / lr;
  const size_t cbase = (size_t)(b * Sn + q0 + q31) * Dn + h * 64;
#pragma unroll
  for (int af = 0; af < 2; ++af)
#pragma unroll
    for (int rg = 0; rg < 4; ++rg) {
      bf16x4 ov;
#pragma unroll
      for (int j = 0; j < 4; ++j) ov[j] = (bf16)(o[af][rg * 4 + j] * inv);
      *(bf16x4*)(ctx + cbase + af * 32 + rg * 8 + 4 * hi) = ov;
    }
}

// ---------------- residual + LayerNorm (ddof=1, /(std+eps)) ----------------
__global__ __launch_bounds__(256) void k_ln(const float* __restrict__ x,
                                            const float* __restrict__ res,
                                            const float* __restrict__ gamma,
                                            const float* __restrict__ beta,
                                            float* __restrict__ yout,
                                            bf16* __restrict__ ybout) {
  const int row = blockIdx.x, t = threadIdx.x;
  const size_t base = (size_t)row * Dn + t * 4;
  f32x4 a = *(const f32x4*)(x + base);
  f32x4 b = *(const f32x4*)(res + base);
  f32x4 vv;
#pragma unroll
  for (int j = 0; j < 4; ++j) vv[j] = a[j] + b[j];

  float s = vv[0] + vv[1] + vv[2] + vv[3];
#pragma unroll
  for (int off = 32; off; off >>= 1) s += __shfl_xor(s, off);
  __shared__ float red1[4], red2[4];
  if ((t & 63) == 0) red1[t >> 6] = s;
  __syncthreads();
  float mean = (red1[0] + red1[1] + red1[2] + red1[3]) * (1.f / 1024.f);

  float d[4], s2 = 0.f;
#pragma unroll
  for (int j = 0; j < 4; ++j) { d[j] = vv[j] - mean; s2 += d[j] * d[j]; }
#pragma unroll
  for (int off = 32; off; off >>= 1) s2 += __shfl_xor(s2, off);
  if ((t & 63) == 0) red2[t >> 6] = s2;
  __syncthreads();
  float var = (red2[0] + red2[1] + red2[2] + red2[3]) * (1.f / 1023.f);
  float inv = 1.f / (sqrtf(var) + 1e-6f);

  f32x4 g = *(const f32x4*)(gamma + t * 4);
  f32x4 bt = *(const f32x4*)(beta + t * 4);
  f32x4 outv;
  bf16x4 outb;
#pragma unroll
  for (int j = 0; j < 4; ++j) {
    float val = g[j] * d[j] * inv + bt[j];
    outv[j] = val;
    outb[j] = (bf16)val;
  }
  *(f32x4*)(yout + base) = outv;
  if (ybout) *(bf16x4*)(ybout + base) = outb;
}

// ---------------- host launcher ----------------
extern "C" void kernel_launch(void* const* d_in, const int* in_sizes, int n_in,
                              void* d_out, int out_size, void* d_ws, size_t ws_size,
                              hipStream_t stream) {
  const float* x   = (const float*)d_in[0];
  const int*   msk = (const int*)d_in[1];
  const float* Wq  = (const float*)d_in[2];
  const float* bq  = (const float*)d_in[3];
  const float* Wk  = (const float*)d_in[4];
  const float* bk  = (const float*)d_in[5];
  const float* Wv  = (const float*)d_in[6];
  const float* bv  = (const float*)d_in[7];
  const float* Wo  = (const float*)d_in[8];
  const float* bo  = (const float*)d_in[9];
  const float* W1  = (const float*)d_in[10];
  const float* b1  = (const float*)d_in[11];
  const float* W2  = (const float*)d_in[12];
  const float* b2  = (const float*)d_in[13];
  const float* g1  = (const float*)d_in[14];
  const float* be1 = (const float*)d_in[15];
  const float* g2  = (const float*)d_in[16];
  const float* be2 = (const float*)d_in[17];
  float* out = (float*)d_out;

  char* w = (char*)d_ws;
  size_t off = 0;
  auto alloc = [&](size_t bytes) { void* p = w + off; off += (bytes + 255) & ~(size_t)255; return p; };
  bf16* xb  = (bf16*)alloc((size_t)Mn * Dn * 2);       // dead after QKV -> vT overlay
  bf16* wqT = (bf16*)alloc((size_t)Dn * Dn * 2);
  bf16* wkT = (bf16*)alloc((size_t)Dn * Dn * 2);
  bf16* wvT = (bf16*)alloc((size_t)Dn * Dn * 2);
  bf16* woT = (bf16*)alloc((size_t)Dn * Dn * 2);
  bf16* w1T = (bf16*)alloc((size_t)Dn * DFFn * 2);
  bf16* w2T = (bf16*)alloc((size_t)DFFn * Dn * 2);
  bf16* qb  = (bf16*)alloc((size_t)Mn * Dn * 2);
  bf16* kb_ = (bf16*)alloc((size_t)Mn * Dn * 2);
  bf16* vb_ = (bf16*)alloc((size_t)Mn * Dn * 2);
  float* attn = (float*)alloc((size_t)Mn * Dn * 4);    // dead after LN1
  float* y    = (float*)alloc((size_t)Mn * Dn * 4);
  bf16* yb    = (bf16*)alloc((size_t)Mn * Dn * 2);
  (void)ws_size; (void)in_sizes; (void)n_in; (void)out_size;
  // overlays (dead-by-then regions):
  bf16* vT  = xb;          // built after QKV GEMMs (xb dead), read by attn
  bf16* ctx = vb_;         // vb_ dead after k_vt; written by attn, read by Wo
  bf16* hh  = qb;          // FF1 out 64MB: spans qb,kb_,vb_(ctx dead),attn head
  float* ff = (float*)w;   // FF2 out 32MB: spans xb/vT + wqT..w1T (all dead)

  // 1. pack x, transpose weights
  k_cvt_bf16<<<(Mn * Dn) / 2048, 256, 0, stream>>>(x, xb);
  dim3 tb(32, 8);
  k_transpose_bf16<<<dim3(32, 32), tb, 0, stream>>>(Wq, wqT, Dn, Dn);
  k_transpose_bf16<<<dim3(32, 32), tb, 0, stream>>>(Wk, wkT, Dn, Dn);
  k_transpose_bf16<<<dim3(32, 32), tb, 0, stream>>>(Wv, wvT, Dn, Dn);
  k_transpose_bf16<<<dim3(32, 32), tb, 0, stream>>>(Wo, woT, Dn, Dn);
  k_transpose_bf16<<<dim3(128, 32), tb, 0, stream>>>(W1, w1T, Dn, DFFn);
  k_transpose_bf16<<<dim3(32, 128), tb, 0, stream>>>(W2, w2T, DFFn, Dn);

  // 2. QKV projections (Q scaled by 0.125*log2e for exp2-domain softmax)
  k_gemm_bt<1, 0><<<dim3(8, 64), 256, 0, stream>>>(xb, wqT, bq, qb, Mn, Dn, Dn, LOG2E_DIV8);
  k_gemm_bt<1, 0><<<dim3(8, 64), 256, 0, stream>>>(xb, wkT, bk, kb_, Mn, Dn, Dn, 1.f);
  k_gemm_bt<1, 0><<<dim3(8, 64), 256, 0, stream>>>(xb, wvT, bv, vb_, Mn, Dn, Dn, 1.f);

  // 3. V transpose + flash attention
  k_vt<<<dim3(Sn / 64, Bn * Hn), 256, 0, stream>>>(vb_, vT);
  k_attn<<<dim3(Sn / 128, Bn * Hn), 256, 0, stream>>>(qb, kb_, vT, msk, ctx);

  // 4. output projection
  k_gemm_bt<0, 0><<<dim3(8, 64), 256, 0, stream>>>(ctx, woT, bo, attn, Mn, Dn, Dn, 1.f);

  // 5. LN1
  k_ln<<<Mn, 256, 0, stream>>>(x, attn, g1, be1, y, yb);

  // 6. FF1
  k_gemm_bt<1, 1><<<dim3(32, 64), 256, 0, stream>>>(yb, w1T, b1, hh, Mn, DFFn, Dn, 1.f);

  // 7. FF2
  k_gemm_bt<0, 0><<<dim3(8, 64), 256, 0, stream>>>(hh, w2T, b2, ff, Mn, Dn, DFFn, 1.f);

  // 8. LN2
  k_ln<<<Mn, 256, 0, stream>>>(y, ff, g2, be2, out, nullptr);
}

// Round 5
// 481.429 us; speedup vs baseline: 1.5750x; 1.1038x over previous
//
#include <hip/hip_runtime.h>

// ---------------- problem constants ----------------
#define Bn 4
#define Sn 2048
#define Dn 1024
#define Hn 16
#define DKn 64
#define DFFn 4096
#define Mn (Bn * Sn) // 8192
#define QKVS 3072    // fused QKV row stride

typedef __bf16 bf16;
typedef __attribute__((ext_vector_type(8))) __bf16 bf16x8;
typedef __attribute__((ext_vector_type(4))) __bf16 bf16x4;
typedef __attribute__((ext_vector_type(8))) unsigned short u16x8;
typedef __attribute__((ext_vector_type(4))) float f32x4;
typedef __attribute__((ext_vector_type(16))) float f32x16;

#define LOG2E_DIV8 0.18033688011112042f  // 0.125 * log2(e)

__device__ __forceinline__ float exp2fast(float x) {
  return __builtin_amdgcn_exp2f(x);
}

// async global->LDS, 16B per lane; LDS dest = wave-uniform base + lane*16
__device__ __forceinline__ void glds16(const bf16* g, bf16* l) {
  __builtin_amdgcn_global_load_lds((const __attribute__((address_space(1))) void*)g,
                                   (__attribute__((address_space(3))) void*)l, 16, 0, 0);
}

__device__ __forceinline__ unsigned int pkbf16(float a, float b) {
  union { __bf16 h[2]; unsigned int u; } x;
  x.h[0] = (__bf16)a; x.h[1] = (__bf16)b;
  return x.u;
}

// ---------------- f32 -> bf16 pack ----------------
__global__ __launch_bounds__(256) void k_cvt_bf16(const float* __restrict__ in,
                                                  bf16* __restrict__ out) {
  size_t i = ((size_t)blockIdx.x * 256 + threadIdx.x) * 8;
  f32x4 a = *(const f32x4*)(in + i);
  f32x4 b = *(const f32x4*)(in + i + 4);
  bf16x8 o;
#pragma unroll
  for (int j = 0; j < 4; ++j) { o[j] = (bf16)a[j]; o[j + 4] = (bf16)b[j]; }
  *(bf16x8*)(out + i) = o;
}

// ---------------- weight transpose: (K,N) f32 -> (N,K) bf16, optional scale ----------------
__global__ __launch_bounds__(256) void k_transpose_bf16(const float* __restrict__ in,
                                                        bf16* __restrict__ out,
                                                        int K, int N, float scale) {
  __shared__ float tile[32][33];
  int n0 = blockIdx.x * 32, k0 = blockIdx.y * 32;
  int tx = threadIdx.x, ty = threadIdx.y;
#pragma unroll
  for (int j = ty; j < 32; j += 8)
    tile[j][tx] = in[(size_t)(k0 + j) * N + n0 + tx];
  __syncthreads();
#pragma unroll
  for (int j = ty; j < 32; j += 8)
    out[(size_t)(n0 + j) * K + k0 + tx] = (bf16)(tile[tx][j] * scale);
}

// ---------------- concat + scale biases for fused QKV ----------------
__global__ __launch_bounds__(256) void k_bias3(const float* __restrict__ bq,
                                               const float* __restrict__ bk,
                                               const float* __restrict__ bv,
                                               float* __restrict__ o) {
  int i = blockIdx.x * 256 + threadIdx.x;
  float v = (i < 1024) ? bq[i] * LOG2E_DIV8
          : (i < 2048) ? bk[i - 1024] : bv[i - 2048];
  o[i] = v;
}

// ---------------- V transpose: v[b*S+s][h*64+dk] (stride vs) -> vT[(bh*64+dk)][s] ----------------
__global__ __launch_bounds__(256) void k_vt(const bf16* __restrict__ v,
                                            bf16* __restrict__ vT, int vs) {
  __shared__ bf16 T[64][72];
  const int t = threadIdx.x;
  const int s0 = blockIdx.x * 64;
  const int bh = blockIdx.y, b = bh >> 4, h = bh & 15;
#pragma unroll
  for (int it = 0; it < 2; ++it) {
    int r = (t >> 3) + it * 32;
    int c = t & 7;
    u16x8 val = *(const u16x8*)(v + (size_t)(b * Sn + s0 + r) * vs + h * 64 + c * 8);
    *(u16x8*)&T[r][c * 8] = val;
  }
  __syncthreads();
#pragma unroll
  for (int it = 0; it < 2; ++it) {
    int d = (t >> 3) + it * 32;
    int cs = t & 7;
    bf16x8 o;
#pragma unroll
    for (int j = 0; j < 8; ++j) o[j] = T[cs * 8 + j][d];
    *(bf16x8*)(vT + ((size_t)bh * 64 + d) * Sn + s0 + cs * 8) = o;
  }
}

// ---------------- 256-row MFMA GEMM, 8 waves, counted-vmcnt 2-deep pipeline ----------------
// BM=256, BN=NFRAG*64, BK=64. Wave (wm,wn) owns rows wm*128..+128, cols wn*NFRAG*16..+NFRAG*16... 
// i.e. wave tile 128 x (16*NFRAG). LDS chunk-XOR swizzle (verified 0-conflict in attn).
template <int NFRAG, int DO_RELU>
__global__ __launch_bounds__(512, 2) void k_gemm256(const bf16* __restrict__ A,
                                                    const bf16* __restrict__ BT,
                                                    const float* __restrict__ bias,
                                                    bf16* __restrict__ C,
                                                    int Ndim, int Kdim) {
  __shared__ __align__(128) bf16 Asm[2][256 * 64];
  __shared__ __align__(128) bf16 Bsm[2][NFRAG * 64 * 64];
  const int tid = threadIdx.x;
  const int wid = tid >> 6, lane = tid & 63;
  const int l15 = lane & 15, l4 = lane >> 4;
  const int wm = wid >> 2, wn = wid & 3;

  // XCD-chunked swizzle (all grids here have nwg % 8 == 0)
  const int gx = gridDim.x;
  int lin = blockIdx.y * gx + blockIdx.x;
  const int nwg = gx * gridDim.y;
  lin = (lin & 7) * (nwg >> 3) + (lin >> 3);
  const int m0 = (lin / gx) * 256;
  const int n0 = (lin % gx) * (NFRAG * 64);

  f32x4 acc[8][NFRAG];
#pragma unroll
  for (int mf = 0; mf < 8; ++mf)
#pragma unroll
    for (int nf = 0; nf < NFRAG; ++nf) acc[mf][nf] = f32x4{0.f, 0.f, 0.f, 0.f};

  // staging lane geometry: 8 rows x 8 chunks per wave-instr; pre-swizzled source chunk
  const int lr = lane >> 3, lc = lane & 7;
  const int NT = Kdim >> 6;

#define STAGE(buf, t)                                                              \
  {                                                                                \
    _Pragma("unroll") for (int it = 0; it < 4; ++it) {                             \
      int r = it * 64 + wid * 8 + lr;                                              \
      int ch = lc ^ (r & 7);                                                       \
      glds16(A + (size_t)(m0 + r) * Kdim + (t) * 64 + ch * 8,                      \
             &Asm[buf][(it * 64 + wid * 8) * 64]);                                 \
    }                                                                              \
    _Pragma("unroll") for (int it = 0; it < NFRAG; ++it) {                         \
      int r = it * 64 + wid * 8 + lr;                                              \
      int ch = lc ^ (r & 7);                                                       \
      glds16(BT + (size_t)(n0 + r) * Kdim + (t) * 64 + ch * 8,                     \
             &Bsm[buf][(it * 64 + wid * 8) * 64]);                                 \
    }                                                                              \
  }

  int p = 0;
  STAGE(0, 0);
  for (int t = 0; t < NT; ++t) {
    if (t + 1 < NT) {
      STAGE(p ^ 1, t + 1);
      // wait only for buf p's loads (issued last iter); t+1's stay in flight
      if constexpr (NFRAG == 4) asm volatile("s_waitcnt vmcnt(8)" ::: "memory");
      else                      asm volatile("s_waitcnt vmcnt(6)" ::: "memory");
    } else {
      asm volatile("s_waitcnt vmcnt(0)" ::: "memory");
    }
    __builtin_amdgcn_sched_barrier(0);
    __builtin_amdgcn_s_barrier();

    // B fragments once per tile
    bf16x8 bfrag[NFRAG][2];
#pragma unroll
    for (int nf = 0; nf < NFRAG; ++nf)
#pragma unroll
      for (int kk = 0; kk < 2; ++kk) {
        int r = wn * (NFRAG * 16) + nf * 16 + l15;
        int ch = (kk * 4 + l4) ^ (r & 7);
        bfrag[nf][kk] = *(const bf16x8*)&Bsm[p][r * 64 + ch * 8];
      }
#pragma unroll
    for (int half = 0; half < 2; ++half) {
      bf16x8 afr[4][2];
#pragma unroll
      for (int mf4 = 0; mf4 < 4; ++mf4)
#pragma unroll
        for (int kk = 0; kk < 2; ++kk) {
          int r = wm * 128 + half * 64 + mf4 * 16 + l15;
          int ch = (kk * 4 + l4) ^ (r & 7);
          afr[mf4][kk] = *(const bf16x8*)&Asm[p][r * 64 + ch * 8];
        }
      __builtin_amdgcn_s_setprio(1);
#pragma unroll
      for (int mf4 = 0; mf4 < 4; ++mf4)
#pragma unroll
        for (int nf = 0; nf < NFRAG; ++nf)
#pragma unroll
          for (int kk = 0; kk < 2; ++kk)
            acc[half * 4 + mf4][nf] = __builtin_amdgcn_mfma_f32_16x16x32_bf16(
                afr[mf4][kk], bfrag[nf][kk], acc[half * 4 + mf4][nf], 0, 0, 0);
      __builtin_amdgcn_s_setprio(0);
    }
    __builtin_amdgcn_s_barrier();  // all waves done reading buf p before it is restaged
    p ^= 1;
  }
#undef STAGE

  // epilogue
#pragma unroll
  for (int mf = 0; mf < 8; ++mf)
#pragma unroll
    for (int nf = 0; nf < NFRAG; ++nf) {
      int c = n0 + wn * (NFRAG * 16) + nf * 16 + l15;
      float bv = bias[c];
      int r0 = m0 + wm * 128 + mf * 16 + l4 * 4;
#pragma unroll
      for (int r = 0; r < 4; ++r) {
        float val = acc[mf][nf][r] + bv;
        if (DO_RELU) val = fmaxf(val, 0.f);
        C[(size_t)(r0 + r) * Ndim + c] = (bf16)val;
      }
    }
}

// ---------------- flash attention, swapped-operand 32x32 MFMA (R4-verified) ----------------
__global__ __launch_bounds__(256) void k_attn(const bf16* __restrict__ q,
                                              const bf16* __restrict__ k,
                                              const bf16* __restrict__ vT,
                                              const int* __restrict__ mask,
                                              bf16* __restrict__ ctx, int qs) {
  __shared__ __align__(128) bf16 Kt[2][64 * 64];
  __shared__ __align__(128) bf16 Vt[2][64 * 64];
  __shared__ float Mb[Sn];
  const int tid = threadIdx.x, wid = tid >> 6, lane = tid & 63;
  const int q31 = lane & 31, hi = lane >> 5;

  int lin = blockIdx.y * gridDim.x + blockIdx.x;  // 1024 blocks
  lin = (lin & 7) * 128 + (lin >> 3);
  const int qblk = lin & 15, bh = lin >> 4;
  const int b = bh >> 4, h = bh & 15;
  const int q0 = qblk * 128 + wid * 32;

  for (int i = tid; i < Sn; i += 256)
    Mb[i] = mask[b * Sn + i] ? 0.f : -1.44269504e9f;

  bf16x8 qf[4];
#pragma unroll
  for (int t = 0; t < 4; ++t)
    qf[t] = *(const bf16x8*)(q + (size_t)(b * Sn + q0 + q31) * qs + h * 64 +
                             t * 16 + hi * 8);

  f32x16 o[2];
  o[0] = {}; o[1] = {};
  float mr = -INFINITY, lr = 0.f;

  const int lrow = lane >> 3;
  const int lch0 = lane & 7;

  for (int kb = 0; kb < Sn / 64; ++kb) {
    const int cur = kb & 1;
    if (kb == 0) {
#pragma unroll
      for (int s = 0; s < 2; ++s) {
        int row = (wid + 4 * s) * 8 + lrow;
        int ch = lch0 ^ (lrow ^ ((wid + 4 * s) & 3));
        glds16(k + (size_t)(b * Sn + row) * qs + h * 64 + ch * 8,
               &Kt[0][(wid + 4 * s) * 512]);
        glds16(vT + ((size_t)bh * 64 + row) * Sn + ch * 8,
               &Vt[0][(wid + 4 * s) * 512]);
      }
      __syncthreads();
    }
    if (kb + 1 < Sn / 64) {
#pragma unroll
      for (int s = 0; s < 2; ++s) {
        int row = (wid + 4 * s) * 8 + lrow;
        int ch = lch0 ^ (lrow ^ ((wid + 4 * s) & 3));
        glds16(k + (size_t)(b * Sn + (kb + 1) * 64 + row) * qs + h * 64 + ch * 8,
               &Kt[cur ^ 1][(wid + 4 * s) * 512]);
        glds16(vT + ((size_t)bh * 64 + row) * Sn + (kb + 1) * 64 + ch * 8,
               &Vt[cur ^ 1][(wid + 4 * s) * 512]);
      }
    }

    f32x16 sc[2];
    sc[0] = {}; sc[1] = {};
#pragma unroll
    for (int t = 0; t < 4; ++t) {
#pragma unroll
      for (int kf = 0; kf < 2; ++kf) {
        int row = kf * 32 + q31;
        int ch = (t * 2 + hi) ^ ((row & 7) ^ ((row >> 3) & 3));
        bf16x8 kfr = *(const bf16x8*)&Kt[cur][row * 64 + ch * 8];
        sc[kf] = __builtin_amdgcn_mfma_f32_32x32x16_bf16(kfr, qf[t], sc[kf], 0, 0, 0);
      }
    }

#pragma unroll
    for (int kf = 0; kf < 2; ++kf)
#pragma unroll
      for (int rg = 0; rg < 4; ++rg) {
        f32x4 mb4 = *(const f32x4*)&Mb[kb * 64 + kf * 32 + rg * 8 + 4 * hi];
#pragma unroll
        for (int j = 0; j < 4; ++j) sc[kf][rg * 4 + j] += mb4[j];
      }

    float rmax = sc[0][0];
#pragma unroll
    for (int kf = 0; kf < 2; ++kf)
#pragma unroll
      for (int i = 0; i < 16; ++i)
        if (kf | i) rmax = fmaxf(rmax, sc[kf][i]);
    rmax = fmaxf(rmax, __shfl_xor(rmax, 32));

    if (!__all(rmax <= mr + 8.f)) {
      float mnew = fmaxf(mr, rmax);
      float psc = exp2fast(mr - mnew);
      mr = mnew;
      lr *= psc;
#pragma unroll
      for (int af = 0; af < 2; ++af)
#pragma unroll
        for (int i = 0; i < 16; ++i) o[af][i] *= psc;
    }

    float psum = 0.f;
#pragma unroll
    for (int kf = 0; kf < 2; ++kf)
#pragma unroll
      for (int i = 0; i < 16; ++i) {
        float p = exp2fast(sc[kf][i] - mr);
        sc[kf][i] = p;
        psum += p;
      }
    psum += __shfl_xor(psum, 32);
    lr += psum;

#pragma unroll
    for (int ks = 0; ks < 4; ++ks) {
      const int kf = ks >> 1, R = (ks & 1) * 8;
      unsigned int a0 = pkbf16(sc[kf][R + 0], sc[kf][R + 1]);
      unsigned int a1 = pkbf16(sc[kf][R + 2], sc[kf][R + 3]);
      unsigned int b0 = pkbf16(sc[kf][R + 4], sc[kf][R + 5]);
      unsigned int b1 = pkbf16(sc[kf][R + 6], sc[kf][R + 7]);
      unsigned int sxa0 = __shfl_xor(a0, 32), sxa1 = __shfl_xor(a1, 32);
      unsigned int sxb0 = __shfl_xor(b0, 32), sxb1 = __shfl_xor(b1, 32);
      union { unsigned int w[4]; bf16x8 v; } pf;
      pf.w[0] = hi ? sxb0 : a0;
      pf.w[1] = hi ? sxb1 : a1;
      pf.w[2] = hi ? b0 : sxa0;
      pf.w[3] = hi ? b1 : sxa1;
#pragma unroll
      for (int af = 0; af < 2; ++af) {
        int row = af * 32 + q31;
        int ch = (ks * 2 + hi) ^ ((row & 7) ^ ((row >> 3) & 3));
        bf16x8 vfr = *(const bf16x8*)&Vt[cur][row * 64 + ch * 8];
        o[af] = __builtin_amdgcn_mfma_f32_32x32x16_bf16(vfr, pf.v, o[af], 0, 0, 0);
      }
    }
    __syncthreads();
  }

  float inv = 1.f / lr;
  const size_t cbase = (size_t)(b * Sn + q0 + q31) * Dn + h * 64;
#pragma unroll
  for (int af = 0; af < 2; ++af)
#pragma unroll
    for (int rg = 0; rg < 4; ++rg) {
      bf16x4 ov;
#pragma unroll
      for (int j = 0; j < 4; ++j) ov[j] = (bf16)(o[af][rg * 4 + j] * inv);
      *(bf16x4*)(ctx + cbase + af * 32 + rg * 8 + 4 * hi) = ov;
    }
}

// ---------------- residual(bf16) + LayerNorm (ddof=1, /(std+eps)) ----------------
__global__ __launch_bounds__(256) void k_ln(const float* __restrict__ x,
                                            const bf16* __restrict__ res,
                                            const float* __restrict__ gamma,
                                            const float* __restrict__ beta,
                                            float* __restrict__ yout,
                                            bf16* __restrict__ ybout) {
  const int row = blockIdx.x, t = threadIdx.x;
  const size_t base = (size_t)row * Dn + t * 4;
  f32x4 a = *(const f32x4*)(x + base);
  bf16x4 rb = *(const bf16x4*)(res + base);
  f32x4 vv;
#pragma unroll
  for (int j = 0; j < 4; ++j) vv[j] = a[j] + (float)rb[j];

  float s = vv[0] + vv[1] + vv[2] + vv[3];
#pragma unroll
  for (int off = 32; off; off >>= 1) s += __shfl_xor(s, off);
  __shared__ float red1[4], red2[4];
  if ((t & 63) == 0) red1[t >> 6] = s;
  __syncthreads();
  float mean = (red1[0] + red1[1] + red1[2] + red1[3]) * (1.f / 1024.f);

  float d[4], s2 = 0.f;
#pragma unroll
  for (int j = 0; j < 4; ++j) { d[j] = vv[j] - mean; s2 += d[j] * d[j]; }
#pragma unroll
  for (int off = 32; off; off >>= 1) s2 += __shfl_xor(s2, off);
  if ((t & 63) == 0) red2[t >> 6] = s2;
  __syncthreads();
  float var = (red2[0] + red2[1] + red2[2] + red2[3]) * (1.f / 1023.f);
  float inv = 1.f / (sqrtf(var) + 1e-6f);

  f32x4 g = *(const f32x4*)(gamma + t * 4);
  f32x4 bt = *(const f32x4*)(beta + t * 4);
  f32x4 outv;
  bf16x4 outb;
#pragma unroll
  for (int j = 0; j < 4; ++j) {
    float val = g[j] * d[j] * inv + bt[j];
    outv[j] = val;
    outb[j] = (bf16)val;
  }
  *(f32x4*)(yout + base) = outv;
  if (ybout) *(bf16x4*)(ybout + base) = outb;
}

// ---------------- host launcher ----------------
extern "C" void kernel_launch(void* const* d_in, const int* in_sizes, int n_in,
                              void* d_out, int out_size, void* d_ws, size_t ws_size,
                              hipStream_t stream) {
  const float* x   = (const float*)d_in[0];
  const int*   msk = (const int*)d_in[1];
  const float* Wq  = (const float*)d_in[2];
  const float* bq  = (const float*)d_in[3];
  const float* Wk  = (const float*)d_in[4];
  const float* bk  = (const float*)d_in[5];
  const float* Wv  = (const float*)d_in[6];
  const float* bv  = (const float*)d_in[7];
  const float* Wo  = (const float*)d_in[8];
  const float* bo  = (const float*)d_in[9];
  const float* W1  = (const float*)d_in[10];
  const float* b1  = (const float*)d_in[11];
  const float* W2  = (const float*)d_in[12];
  const float* b2  = (const float*)d_in[13];
  const float* g1  = (const float*)d_in[14];
  const float* be1 = (const float*)d_in[15];
  const float* g2  = (const float*)d_in[16];
  const float* be2 = (const float*)d_in[17];
  float* out = (float*)d_out;

  char* w = (char*)d_ws;
  size_t off = 0;
  auto alloc = [&](size_t bytes) { void* p = w + off; off += (bytes + 255) & ~(size_t)255; return p; };
  bf16* xb    = (bf16*)alloc((size_t)Mn * Dn * 2);        // 16MB; dead after QKV -> vT overlay
  bf16* wqkvT = (bf16*)alloc((size_t)QKVS * Dn * 2);      // 6MB
  bf16* woT   = (bf16*)alloc((size_t)Dn * Dn * 2);        // 2MB
  bf16* w1T   = (bf16*)alloc((size_t)Dn * DFFn * 2);      // 8MB
  bf16* w2T   = (bf16*)alloc((size_t)DFFn * Dn * 2);      // 8MB
  float* bqkv = (float*)alloc((size_t)QKVS * 4);
  bf16* qkv   = (bf16*)alloc((size_t)Mn * QKVS * 2);      // 48MB; dead after attn -> hh
  bf16* ctx   = (bf16*)alloc((size_t)Mn * Dn * 2);        // 16MB; dead after Wo
  bf16* attnb = (bf16*)alloc((size_t)Mn * Dn * 2);        // 16MB; Wo out, dead after LN1
  float* y    = (float*)alloc((size_t)Mn * Dn * 4);       // 32MB
  bf16* yb    = (bf16*)alloc((size_t)Mn * Dn * 2);        // 16MB
  (void)ws_size; (void)in_sizes; (void)n_in; (void)out_size;
  // overlays (regions dead by the time these are written):
  bf16* vT = xb;          // attn V^T; xb dead after QKV GEMM
  bf16* hh = qkv;         // FF1 out 64MB: spans qkv(48) + ctx(16), both dead
  bf16* ff = xb;          // FF2 out 16MB: xb/vT dead after attn

  // 1. pack x, transpose weights (Wq pre-scaled for exp2-domain softmax), biases
  k_cvt_bf16<<<(Mn * Dn) / 2048, 256, 0, stream>>>(x, xb);
  dim3 tb(32, 8);
  k_transpose_bf16<<<dim3(32, 32), tb, 0, stream>>>(Wq, wqkvT, Dn, Dn, LOG2E_DIV8);
  k_transpose_bf16<<<dim3(32, 32), tb, 0, stream>>>(Wk, wqkvT + (size_t)1024 * Dn, Dn, Dn, 1.f);
  k_transpose_bf16<<<dim3(32, 32), tb, 0, stream>>>(Wv, wqkvT + (size_t)2048 * Dn, Dn, Dn, 1.f);
  k_transpose_bf16<<<dim3(32, 32), tb, 0, stream>>>(Wo, woT, Dn, Dn, 1.f);
  k_transpose_bf16<<<dim3(128, 32), tb, 0, stream>>>(W1, w1T, Dn, DFFn, 1.f);
  k_transpose_bf16<<<dim3(32, 128), tb, 0, stream>>>(W2, w2T, DFFn, Dn, 1.f);
  k_bias3<<<QKVS / 256, 256, 0, stream>>>(bq, bk, bv, bqkv);

  // 2. fused QKV projection: qkv[8192][3072]
  k_gemm256<4, 0><<<dim3(QKVS / 256, Mn / 256), 512, 0, stream>>>(xb, wqkvT, bqkv, qkv, QKVS, Dn);

  // 3. V transpose + flash attention
  k_vt<<<dim3(Sn / 64, Bn * Hn), 256, 0, stream>>>(qkv + 2048, vT, QKVS);
  k_attn<<<dim3(Sn / 128, Bn * Hn), 256, 0, stream>>>(qkv, qkv + 1024, vT, msk, ctx, QKVS);

  // 4. output projection (bf16 out)
  k_gemm256<2, 0><<<dim3(Dn / 128, Mn / 256), 512, 0, stream>>>(ctx, woT, bo, attnb, Dn, Dn);

  // 5. LN1
  k_ln<<<Mn, 256, 0, stream>>>(x, attnb, g1, be1, y, yb);

  // 6. FF1 (relu, bf16 out)
  k_gemm256<4, 1><<<dim3(DFFn / 256, Mn / 256), 512, 0, stream>>>(yb, w1T, b1, hh, DFFn, Dn);

  // 7. FF2 (bf16 out)
  k_gemm256<2, 0><<<dim3(Dn / 128, Mn / 256), 512, 0, stream>>>(hh, w2T, b2, ff, Dn, DFFn);

  // 8. LN2
  k_ln<<<Mn, 256, 0, stream>>>(y, ff, g2, be2, out, nullptr);
}